// Round 9
// baseline (230.891 us; speedup 1.0000x reference)
//
#include <hip/hip_runtime.h>
#include <hip/hip_bf16.h>
#include <math.h>

namespace {

constexpr int BSZ = 2, LEN = 2048, DIM = 2048, NST = 16, RNK = 128;
constexpr int NC = 64, CHUNK = LEN / NC;          // 64 chunks of 32
constexpr int KS = 3 * RNK;                       // split-K = 384
constexpr float LOG2E = 1.4426950408889634f;
constexpr float LN2 = 0.6931471805599453f;

using bf16x8 = __attribute__((ext_vector_type(8))) short;
using f32x4  = __attribute__((ext_vector_type(4))) float;

__device__ __forceinline__ float fast_exp2(float x) {
#if __has_builtin(__builtin_amdgcn_exp2f)
  return __builtin_amdgcn_exp2f(x);
#else
  return exp2f(x);
#endif
}

__device__ __forceinline__ unsigned short bf16_rne(float x) {
  __hip_bfloat16 h = __float2bfloat16(x);
  return *(unsigned short*)&h;
}
__device__ __forceinline__ float bf16_tof(unsigned short u) {
  __hip_bfloat16 h = *(__hip_bfloat16*)&u;
  return __bfloat162float(h);
}

// VALU-pipe cross-lane add (no DS ops). CTRL: 0xB1=xor1, 0x4E=xor2,
// 0x140=row_mirror, 0x141=row_half_mirror -> full 16-lane reduction.
template <int CTRL>
__device__ __forceinline__ float dpp_add_f(float v) {
  int p = __builtin_amdgcn_update_dpp(0, __float_as_int(v), CTRL, 0xF, 0xF, true);
  return v + __int_as_float(p);
}

// ---------- Kernel 0: split f32 -> bf16 hi/lo, padded K=384 layouts ----------
// Ad: [B*L=4096][384] = [hi | lo | hi];  Bd: [D=2048][384] = [hi | hi | lo]
__global__ __launch_bounds__(256)
void split_bf16(const float* __restrict__ delta, const float* __restrict__ W,
                unsigned short* __restrict__ Ad, unsigned short* __restrict__ Bd) {
  int t = blockIdx.x * 256 + threadIdx.x;
  const int NA = BSZ * LEN * RNK;                 // 524288
  if (t < NA) {
    int row = t >> 7, k = t & (RNK - 1);
    float x = delta[t];
    unsigned short hi = bf16_rne(x);
    unsigned short lo = bf16_rne(x - bf16_tof(hi));
    unsigned short* p = Ad + (size_t)row * KS;
    p[k] = hi; p[RNK + k] = lo; p[2 * RNK + k] = hi;
  } else {
    t -= NA;                                      // 262144 W elements
    int row = t >> 7, k = t & (RNK - 1);
    float x = W[t];
    unsigned short hi = bf16_rne(x);
    unsigned short lo = bf16_rne(x - bf16_tof(hi));
    unsigned short* p = Bd + (size_t)row * KS;
    p[k] = hi; p[RNK + k] = hi; p[2 * RNK + k] = lo;
  }
}

// ---------- Kernel 1: dt = softplus(A' @ B'^T + bias) via bf16 MFMA ----------
__global__ __launch_bounds__(256)
void dt_mfma(const unsigned short* __restrict__ Ad, const unsigned short* __restrict__ Bd,
             const float* __restrict__ bias, float* __restrict__ dtout) {
  const int lane = threadIdx.x & 63, wid = threadIdx.x >> 6;
  const int wm = wid >> 1, wn = wid & 1;
  const int bm = blockIdx.x & 31, bn = blockIdx.x >> 5;   // M/128=32, N/128=16
  const int r = lane & 15, kg = lane >> 4;

  const unsigned short* arow = Ad + (size_t)(bm * 128 + wm * 64 + r) * KS + kg * 8;
  const unsigned short* brow = Bd + (size_t)(bn * 128 + wn * 64 + r) * KS + kg * 8;

  f32x4 acc[4][4] = {};
#pragma unroll
  for (int ks = 0; ks < KS / 32; ++ks) {          // 12 k-steps of 32
    bf16x8 af[4], bf[4];
#pragma unroll
    for (int m = 0; m < 4; ++m)
      af[m] = *(const bf16x8*)(arow + (size_t)m * 16 * KS + ks * 32);
#pragma unroll
    for (int n = 0; n < 4; ++n)
      bf[n] = *(const bf16x8*)(brow + (size_t)n * 16 * KS + ks * 32);
#pragma unroll
    for (int m = 0; m < 4; ++m)
#pragma unroll
      for (int n = 0; n < 4; ++n)
        acc[m][n] = __builtin_amdgcn_mfma_f32_16x16x32_bf16(af[m], bf[n], acc[m][n], 0, 0, 0);
  }

#pragma unroll
  for (int n = 0; n < 4; ++n) {
    const int col = bn * 128 + wn * 64 + n * 16 + r;
    const float bs = bias[col];
#pragma unroll
    for (int m = 0; m < 4; ++m) {
      const int row0 = bm * 128 + wm * 64 + m * 16 + kg * 4;
#pragma unroll
      for (int j = 0; j < 4; ++j) {
        float z = acc[m][n][j] + bs;
        float sp = fmaxf(z, 0.f) + LN2 * __log2f(1.0f + fast_exp2(-fabsf(z) * LOG2E));
        dtout[(size_t)(row0 + j) * DIM + col] = sp;
      }
    }
  }
}

// ---------- Kernel 2: persistent sequential scan, one block per (b, 16-d group) ----------
// 256 blocks == 1 per CU. thread = (dl, n): dl = tid>>4, n = tid&15.
// h state lives in ONE register across all 64 chunks; y reduced over the 16
// n-lanes via DPP (VALU pipe, zero DS ops).
__global__ __launch_bounds__(256, 1)
void scan_persist(const float* __restrict__ dtw, const float* __restrict__ x,
                  const float* __restrict__ Bin, const float* __restrict__ Cin,
                  const float* __restrict__ Alog, const float* __restrict__ Dpar,
                  float* __restrict__ out) {
  __shared__ __align__(16) float dt_t[2][16][36];  // [buf][d-local][l], pad 36
  __shared__ __align__(16) float x_t [2][16][36];
  __shared__ __align__(16) float B_t [2][16][36];  // [buf][n][l]
  __shared__ __align__(16) float C_t [2][16][36];
  const int tid = threadIdx.x;
  const int dgrp = blockIdx.x & 127;               // D/16 = 128
  const int b = blockIdx.x >> 7;
  const int dl = tid >> 4, nt = tid & 15;
  const int d = dgrp * 16 + dl;

  const float a2 = -expf(Alog[(size_t)d * NST + nt]) * LOG2E;
  const float dpar = Dpar[d];

  const int srow = tid >> 3;                       // 0..31 (l within chunk)
  const int scol = (tid & 7) * 2;                  // 0,2,..,14 (d-local / n)
  const float* dtp = dtw + (size_t)b * LEN * DIM + dgrp * 16;
  const float* xp  = x   + (size_t)b * LEN * DIM + dgrp * 16;
  const float* Bp  = Bin + (size_t)b * LEN * NST;
  const float* Cp  = Cin + (size_t)b * LEN * NST;

  {  // stage chunk 0
    float2 vdt = *(const float2*)&dtp[(size_t)srow * DIM + scol];
    float2 vx  = *(const float2*)&xp [(size_t)srow * DIM + scol];
    float2 vB  = *(const float2*)&Bp [(size_t)srow * NST + scol];
    float2 vC  = *(const float2*)&Cp [(size_t)srow * NST + scol];
    dt_t[0][scol][srow] = vdt.x; dt_t[0][scol + 1][srow] = vdt.y;
    x_t [0][scol][srow] = vx.x;  x_t [0][scol + 1][srow] = vx.y;
    B_t [0][scol][srow] = vB.x;  B_t [0][scol + 1][srow] = vB.y;
    C_t [0][scol][srow] = vC.x;  C_t [0][scol + 1][srow] = vC.y;
  }
  __syncthreads();

  float h = 0.f;
  float* op = out + (size_t)b * LEN * DIM + d;

  for (int c = 0; c < NC; ++c) {
    const int cur = c & 1, nxt = cur ^ 1;
    const int l0 = c * CHUNK;
    // T14: issue next chunk's global loads before compute; waitcnt lands at the
    // ds_write after the barrier, so HBM latency hides under the scan.
    float2 ndt, nx, nB, nC;
    if (c + 1 < NC) {
      const size_t ro = (size_t)(l0 + CHUNK + srow);
      ndt = *(const float2*)&dtp[ro * DIM + scol];
      nx  = *(const float2*)&xp [ro * DIM + scol];
      nB  = *(const float2*)&Bp [ro * NST + scol];
      nC  = *(const float2*)&Cp [ro * NST + scol];
    }
    float ysv0 = 0.f, ysv1 = 0.f;
#pragma unroll
    for (int i4 = 0; i4 < CHUNK / 4; ++i4) {
      const float4 dtv = *(const float4*)&dt_t[cur][dl][i4 * 4];
      const float4 xv4 = *(const float4*)&x_t [cur][dl][i4 * 4];
      const float4 Bv  = *(const float4*)&B_t [cur][nt][i4 * 4];
      const float4 Cv  = *(const float4*)&C_t [cur][nt][i4 * 4];
#pragma unroll
      for (int ii = 0; ii < 4; ++ii) {
        const int i = i4 * 4 + ii;
        const float dt = (&dtv.x)[ii];
        const float xv = (&xv4.x)[ii];
        const float e  = fast_exp2(dt * a2);
        h = fmaf(e, h, dt * xv * (&Bv.x)[ii]);
        float y = h * (&Cv.x)[ii];
        y = dpp_add_f<0xB1>(y);    // xor1 within quad
        y = dpp_add_f<0x4E>(y);    // xor2 within quad
        y = dpp_add_f<0x140>(y);   // row_mirror: quads 0<->3, 1<->2
        y = dpp_add_f<0x141>(y);   // row_half_mirror: halves of 8
        const float ov = fmaf(xv, dpar, y);
        // lane nt archives row l0+nt and l0+16+nt (compile-time i -> cndmask)
        if ((i & 15) == nt) { if (i < 16) ysv0 = ov; else ysv1 = ov; }
      }
    }
    op[(size_t)(l0 + nt) * DIM] = ysv0;
    op[(size_t)(l0 + 16 + nt) * DIM] = ysv1;
    if (c + 1 < NC) {
      __syncthreads();             // all waves done scanning chunk c
      dt_t[nxt][scol][srow] = ndt.x; dt_t[nxt][scol + 1][srow] = ndt.y;
      x_t [nxt][scol][srow] = nx.x;  x_t [nxt][scol + 1][srow] = nx.y;
      B_t [nxt][scol][srow] = nB.x;  B_t [nxt][scol + 1][srow] = nB.y;
      C_t [nxt][scol][srow] = nC.x;  C_t [nxt][scol + 1][srow] = nC.y;
      __syncthreads();             // staged data visible for chunk c+1
    }
  }
}

}  // namespace

extern "C" void kernel_launch(void* const* d_in, const int* in_sizes, int n_in,
                              void* d_out, int out_size, void* d_ws, size_t ws_size,
                              hipStream_t stream) {
  const float* x     = (const float*)d_in[0];
  const float* delta = (const float*)d_in[1];
  const float* Bin   = (const float*)d_in[2];
  const float* Cin   = (const float*)d_in[3];
  const float* Wdt   = (const float*)d_in[4];
  const float* bdt   = (const float*)d_in[5];
  const float* Alog  = (const float*)d_in[6];
  const float* Dpar  = (const float*)d_in[7];
  float* out = (float*)d_out;

  char* ws = (char*)d_ws;
  size_t off = 0;
  float* dtw = (float*)(ws + off); off += (size_t)BSZ * LEN * DIM * 4;          // 32 MiB
  unsigned short* Ad = (unsigned short*)(ws + off); off += (size_t)BSZ * LEN * KS * 2;  // 3 MiB
  unsigned short* Bd = (unsigned short*)(ws + off); off += (size_t)DIM * KS * 2;        // 1.5 MiB

  split_bf16<<<(BSZ * LEN * RNK + DIM * RNK) / 256, 256, 0, stream>>>(delta, Wdt, Ad, Bd);
  dt_mfma<<<(BSZ * LEN / 128) * (DIM / 128), 256, 0, stream>>>(Ad, Bd, bdt, dtw);
  scan_persist<<<BSZ * (DIM / 16), 256, 0, stream>>>(dtw, x, Bin, Cin, Alog, Dpar, out);
}